// Round 4
// baseline (14500.520 us; speedup 1.0000x reference)
//
#include <hip/hip_runtime.h>
#include <hip/hip_bf16.h>

// Problem constants
#define B_   512
#define T_   256
#define F_   256
#define E_   256
#define H_   256
#define G4_  1024      // 4*H
#define K_   768       // H + E + F  (q | r | x)
#define NS   4         // blocks per group (gate-row split)
#define NG   64        // number of groups
#define GM   8         // molecules per group
#define NTH  256       // threads per block (4 waves)
#define NCROWS 96      // emb rows cached in LDS per owned molecule (3 tiles of 32)

typedef __attribute__((ext_vector_type(8))) short short8;
typedef __attribute__((ext_vector_type(4))) float f32x4;
typedef __attribute__((ext_vector_type(8))) unsigned short ushort8v;
typedef __attribute__((ext_vector_type(2))) unsigned short ushort2v;

__device__ __forceinline__ float bf2f(unsigned int u) {
  union { unsigned int i; float f; } v; v.i = u << 16; return v.f;
}
__device__ __forceinline__ unsigned short f2bf(float f) {
  union { __hip_bfloat16 h; unsigned short u; } v;
  v.h = __float2bfloat16(f); return v.u;
}
__device__ __forceinline__ float sigm(float x) { return 1.f / (1.f + __expf(-x)); }
__device__ __forceinline__ float tanh_fast(float x) { return 1.f - 2.f / (1.f + __expf(2.f * x)); }

// coherent (sc1-bypass) loads for cross-block data — avoid stale L1/L2 without full cache inv
__device__ __forceinline__ short8 aload16s(const unsigned short* p) {
  union { unsigned long long u[2]; short8 v; } x;
  x.u[0] = __hip_atomic_load((const unsigned long long*)p,       __ATOMIC_RELAXED, __HIP_MEMORY_SCOPE_AGENT);
  x.u[1] = __hip_atomic_load((const unsigned long long*)(p + 4), __ATOMIC_RELAXED, __HIP_MEMORY_SCOPE_AGENT);
  return x.v;
}
__device__ __forceinline__ float aloadf(const float* p) {
  union { unsigned int u; float f; } x;
  x.u = __hip_atomic_load((const unsigned int*)p, __ATOMIC_RELAXED, __HIP_MEMORY_SCOPE_AGENT);
  return x.f;
}

__device__ __forceinline__ void waitflag(int* p, int target) {
  if (threadIdx.x == 0) {
    while (__hip_atomic_load(p, __ATOMIC_RELAXED, __HIP_MEMORY_SCOPE_AGENT) < target)
      __builtin_amdgcn_s_sleep(1);
  }
  __syncthreads();
}
__device__ __forceinline__ void bumpflag(int* p) {
  __syncthreads();            // all block threads' global stores drained (vmcnt 0)
  if (threadIdx.x == 0) {
    __threadfence();          // L2 writeback (device scope) — data visible at coherent point
    __hip_atomic_fetch_add(p, 1, __ATOMIC_RELAXED, __HIP_MEMORY_SCOPE_AGENT);
  }
}

// ---------------- setup: pack weights into MFMA B-fragment streams ----------------
__global__ void setup_pack(const float* __restrict__ W_ih, const float* __restrict__ W_hh,
                           const float* __restrict__ b_ih, const float* __restrict__ b_hh,
                           const float* __restrict__ W_att, const float* __restrict__ W_embed,
                           unsigned short* __restrict__ Bg, unsigned short* __restrict__ Ba,
                           unsigned short* __restrict__ We, float* __restrict__ bcomb) {
  int idx = blockIdx.x * blockDim.x + threadIdx.x;
  if (idx < G4_ * K_) {
    int o = idx, j = o & 7, lane = (o >> 3) & 63, rem = o >> 9;
    int kt = rem % 24, rem2 = rem / 24, nt = rem2 & 15, s = rem2 >> 4;
    int n = s * 256 + nt * 16 + (lane & 15);
    int k = kt * 32 + ((lane >> 4) << 3) + j;
    float v = W_ih[n * K_ + k] + (k < H_ ? W_hh[n * H_ + k] : 0.f);
    Bg[o] = f2bf(v);
    return;
  }
  idx -= G4_ * K_;
  if (idx < E_ * H_) {
    int o = idx, j = o & 7, lane = (o >> 3) & 63, rem = o >> 9;
    int kt = rem & 7, nt = rem >> 3;
    int n = nt * 16 + (lane & 15), k = kt * 32 + ((lane >> 4) << 3) + j;
    Ba[o] = f2bf(W_att[n * H_ + k]);
    return;
  }
  idx -= E_ * H_;
  if (idx < E_ * F_) {
    int o = idx, j = o & 7, lane = (o >> 3) & 63, rem = o >> 9;
    int kt = rem & 7, nt = rem >> 3;
    int n = nt * 16 + (lane & 15), k = kt * 32 + ((lane >> 4) << 3) + j;
    We[o] = f2bf(W_embed[n * F_ + k]);
    return;
  }
  idx -= E_ * F_;
  if (idx < G4_) bcomb[idx] = b_ih[idx] + b_hh[idx];
}

// ---------------- deterministic rank sort of lengths -> perm ----------------
__global__ void sort_kernel(const int* __restrict__ lengths, int* __restrict__ perm) {
  __shared__ int lens[B_];
  int tid = threadIdx.x;
  lens[tid] = lengths[tid];
  __syncthreads();
  int L = lens[tid], pos = 0;
  for (int i = 0; i < B_; ++i) {
    int li = lens[i];
    pos += (li < L) || (li == L && i < tid);
  }
  perm[pos] = tid;
}

__global__ void reset_flags(int* flags) {
  flags[blockIdx.x * blockDim.x + threadIdx.x] = 0;
}

// ---------------- main: 64 groups x 4 blocks; 8 mols per group ----------------
__global__ __launch_bounds__(NTH)
void group_kernel(const float* __restrict__ features, const int* __restrict__ lengths,
                  const int* __restrict__ perm,
                  const unsigned short* __restrict__ Bg, const unsigned short* __restrict__ Ba,
                  const unsigned short* __restrict__ We, const float* __restrict__ bcomb,
                  const float* __restrict__ Wfin, const float* __restrict__ bfin,
                  const float* __restrict__ q0, const float* __restrict__ c0,
                  const float* __restrict__ r0,
                  float* __restrict__ gws, unsigned short* __restrict__ qsw,
                  unsigned short* __restrict__ embw, int* __restrict__ flags,
                  float* __restrict__ out) {
  __shared__ unsigned short qs[8][784];                 // q_star A-frags, pad for banks
  __shared__ unsigned short ecache[2][NCROWS][264];     // emb rows 0..95 per owned mol
  __shared__ unsigned short etile[2][32][264];          // streamed emb tiles (dbuf)
  __shared__ float sc32[2][32];
  __shared__ float qp2[2][256];
  __shared__ float cst2[2][256];
  __shared__ unsigned short qnew[2][264];
  __shared__ float redf[4];
  __shared__ float wfv[256];
  __shared__ float bco[1024];
  __shared__ int ids_s[8], lens_s[8];

  const int tid  = threadIdx.x;
  const int w    = tid >> 6;
  const int lane = tid & 63;
  const int g    = blockIdx.x & (NG - 1);
  const int s    = blockIdx.x >> 6;
  int* f1 = flags + g * 32;
  int* f2 = flags + g * 32 + 16;

  if (tid < 8) { int m = perm[g * 8 + tid]; ids_s[tid] = m; lens_s[tid] = lengths[m]; }
  wfv[tid] = Wfin[tid];
  #pragma unroll
  for (int i = 0; i < 4; ++i) bco[i * 256 + tid] = bcomb[i * 256 + tid];
  __syncthreads();
  int lenmax = 1;
  #pragma unroll
  for (int j = 0; j < 8; ++j) lenmax = max(lenmax, lens_s[j]);
  const float bfinal = bfin[0];
  const int molA = ids_s[2 * s], molB = ids_s[2 * s + 1];
  const int lenA = lens_s[2 * s], lenB = lens_s[2 * s + 1];
  const int rankA = g * 8 + 2 * s, rankB = rankA + 1;

  cst2[0][tid] = c0[(size_t)molA * H_ + tid];
  cst2[1][tid] = c0[(size_t)molB * H_ + tid];

  // qstar(0) = [q0 | r0 | x0] bf16, rank-indexed
  qsw[(size_t)rankA * K_ + tid]       = f2bf(q0[(size_t)molA * H_ + tid]);
  qsw[(size_t)rankA * K_ + 256 + tid] = f2bf(r0[(size_t)molA * E_ + tid]);
  qsw[(size_t)rankA * K_ + 512 + tid] = f2bf(features[(size_t)molA * T_ * F_ + tid]);
  qsw[(size_t)rankB * K_ + tid]       = f2bf(q0[(size_t)molB * H_ + tid]);
  qsw[(size_t)rankB * K_ + 256 + tid] = f2bf(r0[(size_t)molB * E_ + tid]);
  qsw[(size_t)rankB * K_ + 512 + tid] = f2bf(features[(size_t)molB * T_ * F_ + tid]);
  bumpflag(f2);

  // ---- embedding via MFMA for the 2 owned mols -> embw ----
  for (int jl = 0; jl < 2; ++jl) {
    const float* fm = features + (size_t)(jl ? molB : molA) * T_ * F_;
    unsigned short* ed = embw + (size_t)(jl ? rankB : rankA) * T_ * E_;
    for (int mt = 0; mt < 16; ++mt) {
      f32x4 ea[4];
      #pragma unroll
      for (int n4 = 0; n4 < 4; ++n4) ea[n4] = f32x4{0.f, 0.f, 0.f, 0.f};
      for (int kt = 0; kt < 8; ++kt) {
        const float* ap_ = fm + (size_t)(mt * 16 + (lane & 15)) * F_ + kt * 32 + ((lane >> 4) << 3);
        float4 fa = *(const float4*)ap_;
        float4 fb = *(const float4*)(ap_ + 4);
        short8 a;
        a[0] = (short)f2bf(fa.x); a[1] = (short)f2bf(fa.y);
        a[2] = (short)f2bf(fa.z); a[3] = (short)f2bf(fa.w);
        a[4] = (short)f2bf(fb.x); a[5] = (short)f2bf(fb.y);
        a[6] = (short)f2bf(fb.z); a[7] = (short)f2bf(fb.w);
        #pragma unroll
        for (int n4 = 0; n4 < 4; ++n4) {
          int nt = w * 4 + n4;
          short8 bb = ((const short8*)We)[(nt * 8 + kt) * 64 + lane];
          ea[n4] = __builtin_amdgcn_mfma_f32_16x16x32_bf16(a, bb, ea[n4], 0, 0, 0);
        }
      }
      #pragma unroll
      for (int n4 = 0; n4 < 4; ++n4) {
        int e = (w * 4 + n4) * 16 + (lane & 15);
        #pragma unroll
        for (int reg = 0; reg < 4; ++reg) {
          int trow = mt * 16 + (lane >> 4) * 4 + reg;
          ed[trow * E_ + e] = f2bf(ea[n4][reg]);
        }
      }
    }
  }
  __syncthreads();
  // fill ecache rows 0..95 for both mols (self-written data)
  for (int jl = 0; jl < 2; ++jl) {
    const unsigned short* ed = embw + (size_t)(jl ? rankB : rankA) * T_ * E_;
    for (int p = 0; p < 3; ++p) {
      int row = p * 32 + (tid >> 3), ch = tid & 7;
      const ushort8v* sp = (const ushort8v*)(ed + row * E_ + ch * 32);
      ushort8v* dp = (ushort8v*)&ecache[jl][row][ch * 32];
      dp[0] = sp[0]; dp[1] = sp[1]; dp[2] = sp[2]; dp[3] = sp[3];
    }
  }

  auto stage_tile = [&](const unsigned short* ed, int ti, int buf) {
    int row = tid >> 3, ch = tid & 7;
    const ushort8v* sp = (const ushort8v*)(ed + (ti * 32 + row) * E_ + ch * 32);
    ushort8v* dp = (ushort8v*)&etile[buf][row][ch * 32];
    dp[0] = sp[0]; dp[1] = sp[1]; dp[2] = sp[2]; dp[3] = sp[3];
  };

  // ---- lockstep recurrence ----
  for (int t = 0; t < lenmax; ++t) {
    waitflag(f2, NS * (t + 1));       // qstar(t) for all 8 group mols ready
    // stage qstar -> LDS (coherent loads)
    {
      int row = tid >> 5, off = (tid & 31) * 24;
      const unsigned short* src = qsw + (size_t)(g * 8 + row) * K_ + off;
      short8 v0 = aload16s(src), v1 = aload16s(src + 8), v2 = aload16s(src + 16);
      *(short8*)&qs[row][off]      = v0;
      *(short8*)&qs[row][off + 8]  = v1;
      *(short8*)&qs[row][off + 16] = v2;
    }
    __syncthreads();

    // gates quarter: rows [s*256,(s+1)*256) for all 8 mols
    {
      f32x4 acc[4];
      #pragma unroll
      for (int n4 = 0; n4 < 4; ++n4) acc[n4] = f32x4{0.f, 0.f, 0.f, 0.f};
      const short8* BW = (const short8*)Bg;
      const int base0 = (s * 16 + w * 4) * 24;
      short8 bc_[4], bn_[4];
      #pragma unroll
      for (int n4 = 0; n4 < 4; ++n4) bc_[n4] = BW[(base0 + n4 * 24) * 64 + lane];
      for (int kt = 0; kt < 24; ++kt) {
        if (kt + 1 < 24) {
          #pragma unroll
          for (int n4 = 0; n4 < 4; ++n4) bn_[n4] = BW[(base0 + n4 * 24 + kt + 1) * 64 + lane];
        }
        short8 a = *(const short8*)&qs[lane & 7][kt * 32 + ((lane >> 4) << 3)];
        #pragma unroll
        for (int n4 = 0; n4 < 4; ++n4)
          acc[n4] = __builtin_amdgcn_mfma_f32_16x16x32_bf16(a, bc_[n4], acc[n4], 0, 0, 0);
        #pragma unroll
        for (int n4 = 0; n4 < 4; ++n4) bc_[n4] = bn_[n4];
      }
      if (lane < 32) {
        int mol0 = (lane >> 4) * 4, col = lane & 15;
        #pragma unroll
        for (int n4 = 0; n4 < 4; ++n4) {
          int n = s * 256 + (w * 4 + n4) * 16 + col;
          #pragma unroll
          for (int reg = 0; reg < 4; ++reg)
            gws[(size_t)(g * 8 + mol0 + reg) * G4_ + n] = acc[n4][reg];
        }
      }
    }
    bumpflag(f1);
    waitflag(f1, NS * (t + 1));       // all quarters ready

    // owner: LSTM elementwise + out for its 2 mols
    for (int jl = 0; jl < 2; ++jl) {
      const int alive = t < (jl ? lenB : lenA);
      if (alive) {
        const float* gw = gws + (size_t)(jl ? rankB : rankA) * G4_;
        float ig = aloadf(gw + tid)       + bco[tid];
        float fg = aloadf(gw + 256 + tid) + bco[256 + tid];
        float gg = aloadf(gw + 512 + tid) + bco[512 + tid];
        float og = aloadf(gw + 768 + tid) + bco[768 + tid];
        float c  = cst2[jl][tid];
        float cn = sigm(fg) * c + sigm(ig) * tanh_fast(gg);
        float qn = sigm(og) * tanh_fast(cn);
        cst2[jl][tid] = cn;
        qnew[jl][tid] = f2bf(qn);
        float po = fmaxf(qn, 0.f) * wfv[tid];
        #pragma unroll
        for (int sh = 32; sh >= 1; sh >>= 1) po += __shfl_xor(po, sh);
        if (lane == 0) redf[w] = po;
      }
      __syncthreads();
      if (alive && tid == 0)
        out[(size_t)(jl ? molB : molA) * T_ + t] = redf[0] + redf[1] + redf[2] + redf[3] + bfinal;
      __syncthreads();
    }

    // qp = W_att @ q for both mols (A rows alternate mol0/mol1)
    {
      f32x4 qa[4];
      #pragma unroll
      for (int n4 = 0; n4 < 4; ++n4) qa[n4] = f32x4{0.f, 0.f, 0.f, 0.f};
      for (int kt = 0; kt < 8; ++kt) {
        short8 a = *(const short8*)&qnew[lane & 1][kt * 32 + ((lane >> 4) << 3)];
        #pragma unroll
        for (int n4 = 0; n4 < 4; ++n4) {
          int nt = w * 4 + n4;
          short8 bb = ((const short8*)Ba)[(nt * 8 + kt) * 64 + lane];
          qa[n4] = __builtin_amdgcn_mfma_f32_16x16x32_bf16(a, bb, qa[n4], 0, 0, 0);
        }
      }
      if (lane < 16) {
        #pragma unroll
        for (int n4 = 0; n4 < 4; ++n4) {
          int e = (w * 4 + n4) * 16 + lane;
          qp2[0][e] = qa[n4][0];
          qp2[1][e] = qa[n4][1];
        }
      }
    }
    __syncthreads();

    // attention per owned mol: LDS-cached rows + streamed tiles, online softmax
    for (int jl = 0; jl < 2; ++jl) {
      const int len = jl ? lenB : lenA;
      if (t < len) {
        const unsigned short* ed = embw + (size_t)(jl ? rankB : rankA) * T_ * E_;
        const int ntile = (len + 31) >> 5;
        float mrun = -3.0e38f, lrun = 0.f, racc = 0.f;
        if (ntile > 3) stage_tile(ed, 3, 0);
        __syncthreads();
        for (int ti = 0; ti < ntile; ++ti) {
          const unsigned short* base =
              (ti < 3) ? &ecache[jl][ti * 32][0] : &etile[(ti - 3) & 1][0][0];
          {
            int rowr = tid >> 3, e0 = (tid & 7) * 32;
            const ushort2v* er = (const ushort2v*)(base + rowr * 264 + e0);
            const float* qh = &qp2[jl][e0];
            float d = 0.f;
            #pragma unroll
            for (int k2 = 0; k2 < 16; ++k2) {
              ushort2v u = er[k2];
              d += bf2f(u[0]) * qh[2 * k2] + bf2f(u[1]) * qh[2 * k2 + 1];
            }
            d += __shfl_xor(d, 1); d += __shfl_xor(d, 2); d += __shfl_xor(d, 4);
            if ((tid & 7) == 0) sc32[ti & 1][rowr] = (ti * 32 + rowr < len) ? d : -3.0e38f;
          }
          if (ti + 1 < ntile && ti + 1 >= 3) stage_tile(ed, ti + 1, (ti + 1 - 3) & 1);
          __syncthreads();
          {
            float tmax = sc32[ti & 1][0];
            #pragma unroll
            for (int r = 1; r < 32; ++r) tmax = fmaxf(tmax, sc32[ti & 1][r]);
            float mnew = fmaxf(mrun, tmax);
            float scale = __expf(mrun - mnew);
            racc *= scale; lrun *= scale;
            float lsum = 0.f;
            #pragma unroll 8
            for (int r = 0; r < 32; ++r) {
              float aw = __expf(sc32[ti & 1][r] - mnew);
              lsum += aw;
              racc += aw * bf2f(base[r * 264 + tid]);
            }
            lrun += lsum; mrun = mnew;
          }
          __syncthreads();
        }
        float rv = racc / lrun;
        unsigned short* qd = qsw + (size_t)(jl ? rankB : rankA) * K_;
        qd[tid]       = qnew[jl][tid];
        qd[256 + tid] = f2bf(rv);
        if (t + 1 < T_)
          qd[512 + tid] = f2bf(features[(size_t)(jl ? molB : molA) * T_ * F_ + (size_t)(t + 1) * F_ + tid]);
      }
      __syncthreads();
    }
    bumpflag(f2);
  }

  // trailing zeros for padded outputs
  for (int jl = 0; jl < 2; ++jl) {
    int len = jl ? lenB : lenA, mol = jl ? molB : molA;
    for (int tt = len + tid; tt < T_; tt += NTH) out[(size_t)mol * T_ + tt] = 0.f;
  }
}

extern "C" void kernel_launch(void* const* d_in, const int* in_sizes, int n_in,
                              void* d_out, int out_size, void* d_ws, size_t ws_size,
                              hipStream_t stream) {
  const float* features = (const float*)d_in[0];
  const int*   lengths  = (const int*)d_in[1];
  const float* W_embed  = (const float*)d_in[2];
  const float* W_ih     = (const float*)d_in[3];
  const float* b_ih     = (const float*)d_in[4];
  const float* W_hh     = (const float*)d_in[5];
  const float* b_hh     = (const float*)d_in[6];
  const float* W_att    = (const float*)d_in[7];
  const float* W_final  = (const float*)d_in[8];
  const float* b_final  = (const float*)d_in[9];
  const float* q0       = (const float*)d_in[10];
  const float* c0       = (const float*)d_in[11];
  const float* r0       = (const float*)d_in[12];
  float* out = (float*)d_out;

  char* ws = (char*)d_ws;
  unsigned short* Bg    = (unsigned short*)(ws + 0);         // 1,572,864
  unsigned short* Ba    = (unsigned short*)(ws + 1572864);   //   131,072
  unsigned short* We    = (unsigned short*)(ws + 1703936);   //   131,072
  float*          bcomb = (float*)(ws + 1835008);            //     4,096
  int*            perm  = (int*)(ws + 1839104);              //     2,048
  int*            flags = (int*)(ws + 1841152);              //     8,192
  float*          gws   = (float*)(ws + 1849344);            // 2,097,152
  unsigned short* qsw   = (unsigned short*)(ws + 3946496);   //   786,432
  unsigned short* embw  = (unsigned short*)(ws + 4732928);   // 67,108,864  (ends ~68.5 MB)

  reset_flags<<<8, 256, 0, stream>>>(flags);
  sort_kernel<<<1, B_, 0, stream>>>(lengths, perm);
  const int setup_elems = G4_ * K_ + E_ * H_ + E_ * F_ + G4_;   // 918,528
  setup_pack<<<(setup_elems + 255) / 256, 256, 0, stream>>>(
      W_ih, W_hh, b_ih, b_hh, W_att, W_embed, Bg, Ba, We, bcomb);
  group_kernel<<<NS * NG, NTH, 0, stream>>>(
      features, lengths, perm, Bg, Ba, We, bcomb,
      W_final, b_final, q0, c0, r0, gws, qsw, embw, flags, out);
}

// Round 5
// 4455.745 us; speedup vs baseline: 3.2543x; 3.2543x over previous
//
#include <hip/hip_runtime.h>
#include <hip/hip_bf16.h>

// Problem constants
#define B_   512
#define T_   256
#define F_   256
#define E_   256
#define H_   256
#define G4_  1024      // 4*H
#define K_   768       // H + E + F  (q | r | x)
#define NT   512       // threads per block (8 waves)
#define NBLK 256       // main kernel blocks (2 molecules each, sequential)

typedef __attribute__((ext_vector_type(8))) short short8;
typedef __attribute__((ext_vector_type(8))) unsigned short ushort8v;
typedef __attribute__((ext_vector_type(4))) float f32x4;

__device__ __forceinline__ float bf2f(unsigned int u) {
  union { unsigned int i; float f; } v; v.i = u << 16; return v.f;
}
__device__ __forceinline__ unsigned short f2bf(float f) {
  union { __hip_bfloat16 h; unsigned short u; } v;
  v.h = __float2bfloat16(f); return v.u;
}
__device__ __forceinline__ float sigm(float x) { return 1.f / (1.f + __expf(-x)); }
__device__ __forceinline__ float tanh_fast(float x) { return 1.f - 2.f / (1.f + __expf(2.f * x)); }

// ---------------- setup: pack weights into MFMA B-fragment streams ----------------
// B-frag layout (16x16x32 bf16): lane holds B[n = lane&15][k = (lane>>4)*8 + j]
// Bg: 1024 rows x 768 cols, frag idx = (ntw*24 + kt), ntw=0..63, kt=0..23
// Bx: 1024 rows x 256 cols (x-part only), frag idx = (ntw*8 + kt)
// Ba: 256 x 256 (W_att), We: 256 x 256 (W_embed), frag idx = (ntw*8 + kt)
__global__ void setup_pack(const float* __restrict__ W_ih, const float* __restrict__ W_hh,
                           const float* __restrict__ b_ih, const float* __restrict__ b_hh,
                           const float* __restrict__ W_att, const float* __restrict__ W_embed,
                           unsigned short* __restrict__ Bg, unsigned short* __restrict__ Bx,
                           unsigned short* __restrict__ Ba, unsigned short* __restrict__ We,
                           float* __restrict__ bcomb) {
  int idx = blockIdx.x * blockDim.x + threadIdx.x;
  if (idx < G4_ * K_) {
    int o = idx, j = o & 7, lane = (o >> 3) & 63, rem = o >> 9;
    int kt = rem % 24, ntw = rem / 24;
    int n = ntw * 16 + (lane & 15);
    int k = kt * 32 + ((lane >> 4) << 3) + j;
    float v = W_ih[n * K_ + k] + (k < H_ ? W_hh[n * H_ + k] : 0.f);
    Bg[o] = f2bf(v);
    return;
  }
  idx -= G4_ * K_;
  if (idx < G4_ * F_) {
    int o = idx, j = o & 7, lane = (o >> 3) & 63, rem = o >> 9;
    int kt = rem & 7, ntw = rem >> 3;
    int n = ntw * 16 + (lane & 15);
    int k = kt * 32 + ((lane >> 4) << 3) + j;
    Bx[o] = f2bf(W_ih[n * K_ + 512 + k]);
    return;
  }
  idx -= G4_ * F_;
  if (idx < E_ * H_) {
    int o = idx, j = o & 7, lane = (o >> 3) & 63, rem = o >> 9;
    int kt = rem & 7, ntw = rem >> 3;
    int n = ntw * 16 + (lane & 15), k = kt * 32 + ((lane >> 4) << 3) + j;
    Ba[o] = f2bf(W_att[n * H_ + k]);
    return;
  }
  idx -= E_ * H_;
  if (idx < E_ * F_) {
    int o = idx, j = o & 7, lane = (o >> 3) & 63, rem = o >> 9;
    int kt = rem & 7, ntw = rem >> 3;
    int n = ntw * 16 + (lane & 15), k = kt * 32 + ((lane >> 4) << 3) + j;
    We[o] = f2bf(W_embed[n * F_ + k]);
    return;
  }
  idx -= E_ * F_;
  if (idx < G4_) bcomb[idx] = b_ih[idx] + b_hh[idx];
}

// ---------------- deterministic rank sort of lengths -> perm ----------------
__global__ void sort_kernel(const int* __restrict__ lengths, int* __restrict__ perm) {
  __shared__ int lens[B_];
  int tid = threadIdx.x;
  lens[tid] = lengths[tid];
  __syncthreads();
  int L = lens[tid], pos = 0;
  for (int i = 0; i < B_; ++i) {
    int li = lens[i];
    pos += (li < L) || (li == L && i < tid);
  }
  perm[pos] = tid;
}

// ---------------- gx precompute: gx[b][t][n] = sum_f W_x[n][f] * x[b][t][f] (bf16) ----
__global__ __launch_bounds__(256)
void gx_kernel(const float* __restrict__ features, const unsigned short* __restrict__ Bx,
               unsigned short* __restrict__ gxw) {
  __shared__ unsigned short featL[T_][264];   // 135168 B
  const int b = blockIdx.x;
  const int tid = threadIdx.x, w = tid >> 6, lane = tid & 63;
  const float* fb = features + (size_t)b * T_ * F_;
  // stage features -> bf16 LDS (thread = row)
  for (int c4 = 0; c4 < 64; ++c4) {
    float4 v = *reinterpret_cast<const float4*>(fb + (size_t)tid * F_ + c4 * 4);
    featL[tid][c4 * 4 + 0] = f2bf(v.x);
    featL[tid][c4 * 4 + 1] = f2bf(v.y);
    featL[tid][c4 * 4 + 2] = f2bf(v.z);
    featL[tid][c4 * 4 + 3] = f2bf(v.w);
  }
  __syncthreads();
  const short8* BX = reinterpret_cast<const short8*>(Bx);
  for (int nt = w; nt < 64; nt += 4) {
    short8 Bf[8];
    #pragma unroll
    for (int kt = 0; kt < 8; ++kt) Bf[kt] = BX[(nt * 8 + kt) * 64 + lane];
    for (int mt = 0; mt < 16; ++mt) {
      f32x4 acc = f32x4{0.f, 0.f, 0.f, 0.f};
      #pragma unroll
      for (int kt = 0; kt < 8; ++kt) {
        short8 a = *reinterpret_cast<const short8*>(
            &featL[mt * 16 + (lane & 15)][kt * 32 + ((lane >> 4) << 3)]);
        acc = __builtin_amdgcn_mfma_f32_16x16x32_bf16(a, Bf[kt], acc, 0, 0, 0);
      }
      #pragma unroll
      for (int reg = 0; reg < 4; ++reg) {
        int t = mt * 16 + (lane >> 4) * 4 + reg;
        gxw[((size_t)b * T_ + t) * G4_ + nt * 16 + (lane & 15)] = f2bf(acc[reg]);
      }
    }
  }
}

// ---------------- main: 256 blocks, 2 length-paired molecules sequentially ----------------
template <int USE_GX>
__global__ __launch_bounds__(NT)
void mol_kernel(const float* __restrict__ features, const int* __restrict__ lengths,
                const int* __restrict__ perm,
                const unsigned short* __restrict__ Bg, const unsigned short* __restrict__ Ba,
                const unsigned short* __restrict__ We, const float* __restrict__ bcomb,
                const float* __restrict__ Wfin, const float* __restrict__ bfin,
                const float* __restrict__ q0, const float* __restrict__ c0,
                const float* __restrict__ r0, const unsigned short* __restrict__ gxw,
                float* __restrict__ out) {
  __shared__ unsigned short emb[T_][264];             // 135168 B
  __shared__ __align__(16) unsigned short qs[784];    // [q|r|(x)] bf16
  __shared__ float gates[G4_];
  __shared__ float qp_s[E_];
  __shared__ float esc[T_];
  __shared__ float psc[T_];
  __shared__ float wf[H_];
  __shared__ float bco[G4_];
  __shared__ float redf[8];

  const int tid  = threadIdx.x;
  const int w    = tid >> 6;
  const int lane = tid & 63;
  const float bfinal = bfin[0];

  if (tid < H_) wf[tid] = Wfin[tid];
  bco[tid] = bcomb[tid];
  bco[tid + 512] = bcomb[tid + 512];

  const short8* BW  = reinterpret_cast<const short8*>(Bg);
  const short8* BA  = reinterpret_cast<const short8*>(Ba);
  const short8* WE  = reinterpret_cast<const short8*>(We);
  const short8* qs8 = reinterpret_cast<const short8*>(qs);

  for (int half = 0; half < 2; ++half) {
    const int b   = perm[half == 0 ? (int)blockIdx.x : (B_ - 1 - (int)blockIdx.x)];
    const int len = lengths[b];
    const float* featb = features + (size_t)b * T_ * F_;
    const unsigned short* gxb = USE_GX ? (gxw + (size_t)b * T_ * G4_) : nullptr;

    // ---- init state ----
    float cstr = 0.f;
    if (tid < H_) {
      cstr = c0[(size_t)b * H_ + tid];
      qs[tid]       = f2bf(q0[(size_t)b * H_ + tid]);
      qs[H_ + tid]  = f2bf(r0[(size_t)b * E_ + tid]);
      esc[tid] = -3.0e38f;                       // rows >= len stay -inf forever
      if (!USE_GX) qs[512 + tid] = f2bf(featb[tid]);   // x_0
    }

    // ---- embedding via MFMA into LDS: emb[t][e], tiles with t-range < len ----
    {
      const int nmt = (len + 15) >> 4;
      for (int mt = 0; mt < nmt; ++mt) {
        f32x4 ea0 = f32x4{0.f, 0.f, 0.f, 0.f};
        f32x4 ea1 = f32x4{0.f, 0.f, 0.f, 0.f};
        #pragma unroll
        for (int kt = 0; kt < 8; ++kt) {
          const float* ap_ = featb + (size_t)(mt * 16 + (lane & 15)) * F_ + kt * 32 + ((lane >> 4) << 3);
          float4 fa = *reinterpret_cast<const float4*>(ap_);
          float4 fb4 = *reinterpret_cast<const float4*>(ap_ + 4);
          short8 a;
          a[0] = (short)f2bf(fa.x);  a[1] = (short)f2bf(fa.y);
          a[2] = (short)f2bf(fa.z);  a[3] = (short)f2bf(fa.w);
          a[4] = (short)f2bf(fb4.x); a[5] = (short)f2bf(fb4.y);
          a[6] = (short)f2bf(fb4.z); a[7] = (short)f2bf(fb4.w);
          ea0 = __builtin_amdgcn_mfma_f32_16x16x32_bf16(a, WE[((2 * w + 0) * 8 + kt) * 64 + lane], ea0, 0, 0, 0);
          ea1 = __builtin_amdgcn_mfma_f32_16x16x32_bf16(a, WE[((2 * w + 1) * 8 + kt) * 64 + lane], ea1, 0, 0, 0);
        }
        #pragma unroll
        for (int reg = 0; reg < 4; ++reg) {
          int t = mt * 16 + (lane >> 4) * 4 + reg;
          emb[t][(2 * w + 0) * 16 + (lane & 15)] = f2bf(ea0[reg]);
          emb[t][(2 * w + 1) * 16 + (lane & 15)] = f2bf(ea1[reg]);
        }
      }
    }

    // ---- recurrence ----
    for (int t = 0; t < len; ++t) {
      __syncthreads();   // B1: qs(t), emb, esc-init ready

      // issue per-step global loads early (latency hidden under MFMA)
      unsigned short gxu0 = 0, gxu1 = 0, gxu2 = 0, gxu3 = 0;
      float xnext = 0.f;
      if (USE_GX) {
        if (tid < H_) {
          const unsigned short* gp = gxb + (size_t)t * G4_ + tid;
          gxu0 = gp[0]; gxu1 = gp[256]; gxu2 = gp[512]; gxu3 = gp[768];
        }
      } else {
        if (tid < H_ && t + 1 < T_) xnext = featb[(size_t)(t + 1) * F_ + tid];
      }

      // phase 1: gates MFMA (A = qstar replicated over 16 M rows)
      {
        const int KTL = USE_GX ? 16 : 24;
        f32x4 acc[8];
        #pragma unroll
        for (int nt = 0; nt < 8; ++nt) acc[nt] = f32x4{0.f, 0.f, 0.f, 0.f};
        short8 cur[8], nxt[8];
        #pragma unroll
        for (int nt = 0; nt < 8; ++nt) cur[nt] = BW[((w * 8 + nt) * 24 + 0) * 64 + lane];
        for (int kt = 0; kt < KTL; ++kt) {
          if (kt + 1 < KTL) {
            #pragma unroll
            for (int nt = 0; nt < 8; ++nt) nxt[nt] = BW[((w * 8 + nt) * 24 + kt + 1) * 64 + lane];
          }
          short8 a = qs8[kt * 4 + (lane >> 4)];
          #pragma unroll
          for (int nt = 0; nt < 8; ++nt)
            acc[nt] = __builtin_amdgcn_mfma_f32_16x16x32_bf16(a, cur[nt], acc[nt], 0, 0, 0);
          #pragma unroll
          for (int nt = 0; nt < 8; ++nt) cur[nt] = nxt[nt];
        }
        if (lane < 16) {
          #pragma unroll
          for (int nt = 0; nt < 8; ++nt) gates[w * 128 + nt * 16 + lane] = acc[nt][0];
        }
      }
      __syncthreads();   // B2: gates ready

      // phase 2: LSTM elementwise (tid<256), q->qs[0:256], out-partial
      if (tid < H_) {
        float ig = gates[tid]           + bco[tid];
        float fg = gates[H_ + tid]      + bco[H_ + tid];
        float gg = gates[2 * H_ + tid]  + bco[2 * H_ + tid];
        float og = gates[3 * H_ + tid]  + bco[3 * H_ + tid];
        if (USE_GX) {
          ig += bf2f(gxu0); fg += bf2f(gxu1); gg += bf2f(gxu2); og += bf2f(gxu3);
        }
        float cn = sigm(fg) * cstr + sigm(ig) * tanh_fast(gg);
        float qn = sigm(og) * tanh_fast(cn);
        cstr = cn;
        qs[tid] = f2bf(qn);
        float po = fmaxf(qn, 0.f) * wf[tid];
        #pragma unroll
        for (int s = 32; s >= 1; s >>= 1) po += __shfl_xor(po, s);
        if (lane == 0) redf[w] = po;
      }
      __syncthreads();   // B3: qnew + redf ready

      // phase 3: out write + qp = W_att @ qnew via MFMA
      if (tid == 0) out[(size_t)b * T_ + t] = redf[0] + redf[1] + redf[2] + redf[3] + bfinal;
      {
        f32x4 a0 = f32x4{0.f, 0.f, 0.f, 0.f};
        f32x4 a1 = f32x4{0.f, 0.f, 0.f, 0.f};
        #pragma unroll
        for (int kt = 0; kt < 8; ++kt) {
          short8 a = qs8[kt * 4 + (lane >> 4)];
          a0 = __builtin_amdgcn_mfma_f32_16x16x32_bf16(a, BA[((2 * w + 0) * 8 + kt) * 64 + lane], a0, 0, 0, 0);
          a1 = __builtin_amdgcn_mfma_f32_16x16x32_bf16(a, BA[((2 * w + 1) * 8 + kt) * 64 + lane], a1, 0, 0, 0);
        }
        if (lane < 16) {
          qp_s[(2 * w + 0) * 16 + lane] = a0[0];
          qp_s[(2 * w + 1) * 16 + lane] = a1[0];
        }
      }
      __syncthreads();   // B4: qp ready

      // phase 4: scores esc[tv] = emb[tv,:] . qp   (2 threads per row)
      {
        const int tv = tid >> 1, hf = tid & 1;
        if (tv < len) {
          const ushort8v* er = reinterpret_cast<const ushort8v*>(&emb[tv][hf * 128]);
          float d = 0.f;
          #pragma unroll
          for (int k8 = 0; k8 < 16; ++k8) {
            ushort8v u = er[k8];
            const float* qh = &qp_s[hf * 128 + k8 * 8];
            d += bf2f(u[0]) * qh[0] + bf2f(u[1]) * qh[1] + bf2f(u[2]) * qh[2] + bf2f(u[3]) * qh[3]
               + bf2f(u[4]) * qh[4] + bf2f(u[5]) * qh[5] + bf2f(u[6]) * qh[6] + bf2f(u[7]) * qh[7];
          }
          d += __shfl_xor(d, 1);
          if (hf == 0) esc[tv] = d;
        }
      }
      __syncthreads();   // B5: esc ready

      // phase 5: softmax m/denom (redundant per wave, butterfly), p -> psc
      float rinv;
      {
        float v0 = esc[lane], v1 = esc[lane + 64], v2 = esc[lane + 128], v3 = esc[lane + 192];
        float m = fmaxf(fmaxf(v0, v1), fmaxf(v2, v3));
        #pragma unroll
        for (int s = 32; s >= 1; s >>= 1) m = fmaxf(m, __shfl_xor(m, s));
        float p0 = __expf(v0 - m), p1 = __expf(v1 - m), p2 = __expf(v2 - m), p3 = __expf(v3 - m);
        float sv = p0 + p1 + p2 + p3;
        #pragma unroll
        for (int s = 32; s >= 1; s >>= 1) sv += __shfl_xor(sv, s);
        rinv = 1.f / sv;
        if (w < 4) psc[lane + (w << 6)] = (w == 0) ? p0 : (w == 1) ? p1 : (w == 2) ? p2 : p3;
      }
      __syncthreads();   // B6: psc ready

      // phase 6: r[e] = (sum_t p[t]*emb[t][e]) * rinv -> qs[256+e]; x prefetch -> qs[512+]
      {
        const int e = tid >> 1, hf = tid & 1;
        const int tlo = hf * 128;
        const int thi = (len < tlo + 128) ? len : (tlo + 128);
        float acc = 0.f;
        for (int tt = tlo; tt < thi; ++tt) acc += psc[tt] * bf2f(emb[tt][e]);
        acc += __shfl_xor(acc, 1);
        if (hf == 0) qs[H_ + e] = f2bf(acc * rinv);
      }
      if (!USE_GX && tid < H_) qs[512 + tid] = f2bf(xnext);
      // loop-top barrier (B1) fences qs writes
    }

    // zero padded outputs
    for (int tt = len + tid; tt < T_; tt += NT) out[(size_t)b * T_ + tt] = 0.f;
    __syncthreads();   // emb/qs/esc reuse fence before next molecule
  }
}

extern "C" void kernel_launch(void* const* d_in, const int* in_sizes, int n_in,
                              void* d_out, int out_size, void* d_ws, size_t ws_size,
                              hipStream_t stream) {
  const float* features = (const float*)d_in[0];
  const int*   lengths  = (const int*)d_in[1];
  const float* W_embed  = (const float*)d_in[2];
  const float* W_ih     = (const float*)d_in[3];
  const float* b_ih     = (const float*)d_in[4];
  const float* W_hh     = (const float*)d_in[5];
  const float* b_hh     = (const float*)d_in[6];
  const float* W_att    = (const float*)d_in[7];
  const float* W_final  = (const float*)d_in[8];
  const float* b_final  = (const float*)d_in[9];
  const float* q0       = (const float*)d_in[10];
  const float* c0       = (const float*)d_in[11];
  const float* r0       = (const float*)d_in[12];
  float* out = (float*)d_out;

  char* ws = (char*)d_ws;
  unsigned short* Bg    = (unsigned short*)(ws + 0);          // 1,572,864
  unsigned short* Bx    = (unsigned short*)(ws + 1572864);    //   524,288
  unsigned short* Ba    = (unsigned short*)(ws + 2097152);    //   131,072
  unsigned short* We    = (unsigned short*)(ws + 2228224);    //   131,072
  float*          bcomb = (float*)(ws + 2359296);             //     4,096
  int*            perm  = (int*)(ws + 2363392);               //     2,048
  unsigned short* gxw   = (unsigned short*)(ws + 2365440);    // 268,435,456
  const size_t need_gx = 2365440ull + 268435456ull;
  const int use_gx = (ws_size >= need_gx) ? 1 : 0;

  const int setup_elems = G4_ * K_ + G4_ * F_ + E_ * H_ + E_ * F_ + G4_;  // 1,180,672
  setup_pack<<<(setup_elems + 255) / 256, 256, 0, stream>>>(
      W_ih, W_hh, b_ih, b_hh, W_att, W_embed, Bg, Bx, Ba, We, bcomb);
  sort_kernel<<<1, B_, 0, stream>>>(lengths, perm);
  if (use_gx) {
    gx_kernel<<<B_, 256, 0, stream>>>(features, Bx, gxw);
    mol_kernel<1><<<NBLK, NT, 0, stream>>>(
        features, lengths, perm, Bg, Ba, We, bcomb,
        W_final, b_final, q0, c0, r0, gxw, out);
  } else {
    mol_kernel<0><<<NBLK, NT, 0, stream>>>(
        features, lengths, perm, Bg, Ba, We, bcomb,
        W_final, b_final, q0, c0, r0, gxw, out);
  }
}

// Round 6
// 3265.736 us; speedup vs baseline: 4.4402x; 1.3644x over previous
//
#include <hip/hip_runtime.h>
#include <hip/hip_bf16.h>

// Problem constants
#define B_   512
#define T_   256
#define F_   256
#define E_   256
#define H_   256
#define G4_  1024      // 4*H
#define K_   768       // H + E + F  (q | r | x)
#define NT   512       // threads per block (8 waves)
#define NBLK 256       // main kernel blocks (2 molecules each, sequential)

typedef __attribute__((ext_vector_type(8))) short short8;
typedef __attribute__((ext_vector_type(8))) unsigned short ushort8v;
typedef __attribute__((ext_vector_type(4))) unsigned short ushort4v;
typedef __attribute__((ext_vector_type(4))) float f32x4;

__device__ __forceinline__ float bf2f(unsigned int u) {
  union { unsigned int i; float f; } v; v.i = u << 16; return v.f;
}
__device__ __forceinline__ unsigned short f2bf(float f) {
  union { __hip_bfloat16 h; unsigned short u; } v;
  v.h = __float2bfloat16(f); return v.u;
}
__device__ __forceinline__ float sigm(float x) { return 1.f / (1.f + __expf(-x)); }
__device__ __forceinline__ float tanh_fast(float x) { return 1.f - 2.f / (1.f + __expf(2.f * x)); }

// ---------------- setup: pack weights into MFMA B-fragment streams ----------------
// B-frag layout (16x16x32 bf16): lane holds B[n = lane&15][k = (lane>>4)*8 + j]
__global__ void setup_pack(const float* __restrict__ W_ih, const float* __restrict__ W_hh,
                           const float* __restrict__ b_ih, const float* __restrict__ b_hh,
                           const float* __restrict__ W_att, const float* __restrict__ W_embed,
                           unsigned short* __restrict__ Bg, unsigned short* __restrict__ Bx,
                           unsigned short* __restrict__ Ba, unsigned short* __restrict__ We,
                           float* __restrict__ bcomb) {
  int idx = blockIdx.x * blockDim.x + threadIdx.x;
  if (idx < G4_ * K_) {
    int o = idx, j = o & 7, lane = (o >> 3) & 63, rem = o >> 9;
    int kt = rem % 24, ntw = rem / 24;
    int n = ntw * 16 + (lane & 15);
    int k = kt * 32 + ((lane >> 4) << 3) + j;
    float v = W_ih[n * K_ + k] + (k < H_ ? W_hh[n * H_ + k] : 0.f);
    Bg[o] = f2bf(v);
    return;
  }
  idx -= G4_ * K_;
  if (idx < G4_ * F_) {
    int o = idx, j = o & 7, lane = (o >> 3) & 63, rem = o >> 9;
    int kt = rem & 7, ntw = rem >> 3;
    int n = ntw * 16 + (lane & 15);
    int k = kt * 32 + ((lane >> 4) << 3) + j;
    Bx[o] = f2bf(W_ih[n * K_ + 512 + k]);
    return;
  }
  idx -= G4_ * F_;
  if (idx < E_ * H_) {
    int o = idx, j = o & 7, lane = (o >> 3) & 63, rem = o >> 9;
    int kt = rem & 7, ntw = rem >> 3;
    int n = ntw * 16 + (lane & 15), k = kt * 32 + ((lane >> 4) << 3) + j;
    Ba[o] = f2bf(W_att[n * H_ + k]);
    return;
  }
  idx -= E_ * H_;
  if (idx < E_ * F_) {
    int o = idx, j = o & 7, lane = (o >> 3) & 63, rem = o >> 9;
    int kt = rem & 7, ntw = rem >> 3;
    int n = ntw * 16 + (lane & 15), k = kt * 32 + ((lane >> 4) << 3) + j;
    We[o] = f2bf(W_embed[n * F_ + k]);
    return;
  }
  idx -= E_ * F_;
  if (idx < G4_) bcomb[idx] = b_ih[idx] + b_hh[idx];
}

// ---------------- deterministic rank sort of lengths -> perm ----------------
__global__ void sort_kernel(const int* __restrict__ lengths, int* __restrict__ perm) {
  __shared__ int lens[B_];
  int tid = threadIdx.x;
  lens[tid] = lengths[tid];
  __syncthreads();
  int L = lens[tid], pos = 0;
  for (int i = 0; i < B_; ++i) {
    int li = lens[i];
    pos += (li < L) || (li == L && i < tid);
  }
  perm[pos] = tid;
}

// ---------------- gx precompute: gx[b][t][n] = sum_f W_x[n][f] * x[b][t][f] (bf16) ----
__global__ __launch_bounds__(256)
void gx_kernel(const float* __restrict__ features, const unsigned short* __restrict__ Bx,
               unsigned short* __restrict__ gxw) {
  __shared__ unsigned short featL[T_][264];   // 135168 B
  const int b = blockIdx.x;
  const int tid = threadIdx.x, w = tid >> 6, lane = tid & 63;
  const float* fb = features + (size_t)b * T_ * F_;
  for (int c4 = 0; c4 < 64; ++c4) {
    float4 v = *reinterpret_cast<const float4*>(fb + (size_t)tid * F_ + c4 * 4);
    featL[tid][c4 * 4 + 0] = f2bf(v.x);
    featL[tid][c4 * 4 + 1] = f2bf(v.y);
    featL[tid][c4 * 4 + 2] = f2bf(v.z);
    featL[tid][c4 * 4 + 3] = f2bf(v.w);
  }
  __syncthreads();
  const short8* BX = reinterpret_cast<const short8*>(Bx);
  for (int nt = w; nt < 64; nt += 4) {
    short8 Bf[8];
    #pragma unroll
    for (int kt = 0; kt < 8; ++kt) Bf[kt] = BX[(nt * 8 + kt) * 64 + lane];
    for (int mt = 0; mt < 16; ++mt) {
      f32x4 acc = f32x4{0.f, 0.f, 0.f, 0.f};
      #pragma unroll
      for (int kt = 0; kt < 8; ++kt) {
        short8 a = *reinterpret_cast<const short8*>(
            &featL[mt * 16 + (lane & 15)][kt * 32 + ((lane >> 4) << 3)]);
        acc = __builtin_amdgcn_mfma_f32_16x16x32_bf16(a, Bf[kt], acc, 0, 0, 0);
      }
      #pragma unroll
      for (int reg = 0; reg < 4; ++reg) {
        int t = mt * 16 + (lane >> 4) * 4 + reg;
        gxw[((size_t)b * T_ + t) * G4_ + nt * 16 + (lane & 15)] = f2bf(acc[reg]);
      }
    }
  }
}

// ---------------- main: 256 blocks, 2 length-paired molecules sequentially ----------------
template <int USE_GX>
__global__ __launch_bounds__(NT, 2)
void mol_kernel(const float* __restrict__ features, const int* __restrict__ lengths,
                const int* __restrict__ perm,
                const unsigned short* __restrict__ Bg, const unsigned short* __restrict__ Ba,
                const unsigned short* __restrict__ We, const float* __restrict__ bcomb,
                const float* __restrict__ Wfin, const float* __restrict__ bfin,
                const float* __restrict__ q0, const float* __restrict__ c0,
                const float* __restrict__ r0, const unsigned short* __restrict__ gxw,
                float* __restrict__ out) {
  __shared__ __align__(16) unsigned short emb[T_][264];   // 135168 B
  __shared__ __align__(16) unsigned short qs[784];        // [q|r|(x)] bf16
  __shared__ __align__(16) unsigned short qpb[272];       // qp bf16
  __shared__ float gates[G4_];
  __shared__ float esc[T_];
  __shared__ float psc[T_];
  __shared__ float rpart[8][264];                         // 8448 B
  __shared__ float wf[H_];
  __shared__ float bco[G4_];
  __shared__ float redf[8];

  const int tid  = threadIdx.x;
  const int w    = tid >> 6;
  const int lane = tid & 63;
  const float bfinal = bfin[0];

  if (tid < H_) wf[tid] = Wfin[tid];
  bco[tid] = bcomb[tid];
  bco[tid + 512] = bcomb[tid + 512];

  const short8* BW  = reinterpret_cast<const short8*>(Bg);
  const short8* BA  = reinterpret_cast<const short8*>(Ba);
  const short8* WE  = reinterpret_cast<const short8*>(We);
  const short8* qs8 = reinterpret_cast<const short8*>(qs);

  // W_att B-frags resident in VGPRs (constant across steps/molecules): 64 VGPR
  short8 barf0[8], barf1[8];
  #pragma unroll
  for (int kt = 0; kt < 8; ++kt) {
    barf0[kt] = BA[((2 * w + 0) * 8 + kt) * 64 + lane];
    barf1[kt] = BA[((2 * w + 1) * 8 + kt) * 64 + lane];
  }

  for (int half = 0; half < 2; ++half) {
    const int b   = perm[half == 0 ? (int)blockIdx.x : (B_ - 1 - (int)blockIdx.x)];
    const int len = lengths[b];
    const float* featb = features + (size_t)b * T_ * F_;
    const unsigned short* gxb = USE_GX ? (gxw + (size_t)b * T_ * G4_) : nullptr;
    const int nmt = (len + 15) >> 4;

    // ---- init state ----
    float cstr = 0.f;
    if (tid < H_) {
      cstr = c0[(size_t)b * H_ + tid];
      qs[tid]       = f2bf(q0[(size_t)b * H_ + tid]);
      qs[H_ + tid]  = f2bf(r0[(size_t)b * E_ + tid]);
      esc[tid] = -3.0e38f;                       // rows never written stay -inf
      if (!USE_GX) qs[512 + tid] = f2bf(featb[tid]);   // x_0
    }

    // ---- embedding via MFMA into LDS: emb[t][e] for tiles with t < len ----
    for (int mt = 0; mt < nmt; ++mt) {
      f32x4 ea0 = f32x4{0.f, 0.f, 0.f, 0.f};
      f32x4 ea1 = f32x4{0.f, 0.f, 0.f, 0.f};
      #pragma unroll
      for (int kt = 0; kt < 8; ++kt) {
        const float* ap_ = featb + (size_t)(mt * 16 + (lane & 15)) * F_ + kt * 32 + ((lane >> 4) << 3);
        float4 fa = *reinterpret_cast<const float4*>(ap_);
        float4 fb4 = *reinterpret_cast<const float4*>(ap_ + 4);
        short8 a;
        a[0] = (short)f2bf(fa.x);  a[1] = (short)f2bf(fa.y);
        a[2] = (short)f2bf(fa.z);  a[3] = (short)f2bf(fa.w);
        a[4] = (short)f2bf(fb4.x); a[5] = (short)f2bf(fb4.y);
        a[6] = (short)f2bf(fb4.z); a[7] = (short)f2bf(fb4.w);
        ea0 = __builtin_amdgcn_mfma_f32_16x16x32_bf16(a, WE[((2 * w + 0) * 8 + kt) * 64 + lane], ea0, 0, 0, 0);
        ea1 = __builtin_amdgcn_mfma_f32_16x16x32_bf16(a, WE[((2 * w + 1) * 8 + kt) * 64 + lane], ea1, 0, 0, 0);
      }
      #pragma unroll
      for (int reg = 0; reg < 4; ++reg) {
        int t = mt * 16 + (lane >> 4) * 4 + reg;
        emb[t][(2 * w + 0) * 16 + (lane & 15)] = f2bf(ea0[reg]);
        emb[t][(2 * w + 1) * 16 + (lane & 15)] = f2bf(ea1[reg]);
      }
    }

    // ---- recurrence ----
    for (int t = 0; t < len; ++t) {
      __syncthreads();   // B1: qs(t), emb, esc ready

      // early per-step global loads (latency hidden under phase 1)
      unsigned short gxu0 = 0, gxu1 = 0, gxu2 = 0, gxu3 = 0;
      float xnext = 0.f;
      if (USE_GX) {
        if (tid < H_) {
          const unsigned short* gp = gxb + (size_t)t * G4_ + tid;
          gxu0 = gp[0]; gxu1 = gp[256]; gxu2 = gp[512]; gxu3 = gp[768];
        }
      } else {
        if (tid < H_ && t + 1 < T_) xnext = featb[(size_t)(t + 1) * F_ + tid];
      }

      // phase 1: gates MFMA (A = qstar replicated over 16 M rows)
      {
        const int KTL = USE_GX ? 16 : 24;
        f32x4 acc[8];
        #pragma unroll
        for (int nt = 0; nt < 8; ++nt) acc[nt] = f32x4{0.f, 0.f, 0.f, 0.f};
        short8 cur[8], nxt[8];
        #pragma unroll
        for (int nt = 0; nt < 8; ++nt) cur[nt] = BW[((w * 8 + nt) * 24 + 0) * 64 + lane];
        for (int kt = 0; kt < KTL; ++kt) {
          if (kt + 1 < KTL) {
            #pragma unroll
            for (int nt = 0; nt < 8; ++nt) nxt[nt] = BW[((w * 8 + nt) * 24 + kt + 1) * 64 + lane];
          }
          short8 a = qs8[kt * 4 + (lane >> 4)];
          #pragma unroll
          for (int nt = 0; nt < 8; ++nt)
            acc[nt] = __builtin_amdgcn_mfma_f32_16x16x32_bf16(a, cur[nt], acc[nt], 0, 0, 0);
          #pragma unroll
          for (int nt = 0; nt < 8; ++nt) cur[nt] = nxt[nt];
        }
        if (lane < 16) {
          #pragma unroll
          for (int nt = 0; nt < 8; ++nt) gates[w * 128 + nt * 16 + lane] = acc[nt][0];
        }
      }
      __syncthreads();   // B2: gates ready

      // phase 2: LSTM elementwise (tid<256), q -> qs[0:256], out-partial
      if (tid < H_) {
        float ig = gates[tid]           + bco[tid];
        float fg = gates[H_ + tid]      + bco[H_ + tid];
        float gg = gates[2 * H_ + tid]  + bco[2 * H_ + tid];
        float og = gates[3 * H_ + tid]  + bco[3 * H_ + tid];
        if (USE_GX) {
          ig += bf2f(gxu0); fg += bf2f(gxu1); gg += bf2f(gxu2); og += bf2f(gxu3);
        }
        float cn = sigm(fg) * cstr + sigm(ig) * tanh_fast(gg);
        float qn = sigm(og) * tanh_fast(cn);
        cstr = cn;
        qs[tid] = f2bf(qn);
        float po = fmaxf(qn, 0.f) * wf[tid];
        #pragma unroll
        for (int s = 32; s >= 1; s >>= 1) po += __shfl_xor(po, s);
        if (lane == 0) redf[w] = po;
      }
      __syncthreads();   // B3: qnew + redf ready

      // phase 3: out write + qp = W_att @ qnew (resident B-frags) -> qpb bf16
      if (tid == 0) out[(size_t)b * T_ + t] = redf[0] + redf[1] + redf[2] + redf[3] + bfinal;
      {
        f32x4 a0 = f32x4{0.f, 0.f, 0.f, 0.f};
        f32x4 a1 = f32x4{0.f, 0.f, 0.f, 0.f};
        #pragma unroll
        for (int kt = 0; kt < 8; ++kt) {
          short8 a = qs8[kt * 4 + (lane >> 4)];
          a0 = __builtin_amdgcn_mfma_f32_16x16x32_bf16(a, barf0[kt], a0, 0, 0, 0);
          a1 = __builtin_amdgcn_mfma_f32_16x16x32_bf16(a, barf1[kt], a1, 0, 0, 0);
        }
        if (lane < 16) {
          qpb[(2 * w + 0) * 16 + lane] = f2bf(a0[0]);
          qpb[(2 * w + 1) * 16 + lane] = f2bf(a1[0]);
        }
      }
      __syncthreads();   // B4: qpb ready

      // phase 4: scores via MFMA (A = emb rows from LDS, B = qp broadcast)
      {
        #pragma unroll
        for (int h4 = 0; h4 < 2; ++h4) {
          const int mt = 2 * w + h4;
          if (mt < nmt) {
            f32x4 acc = f32x4{0.f, 0.f, 0.f, 0.f};
            #pragma unroll
            for (int kt = 0; kt < 8; ++kt) {
              short8 a  = *reinterpret_cast<const short8*>(
                  &emb[mt * 16 + (lane & 15)][kt * 32 + ((lane >> 4) << 3)]);
              short8 bq = *reinterpret_cast<const short8*>(
                  &qpb[kt * 32 + ((lane >> 4) << 3)]);
              acc = __builtin_amdgcn_mfma_f32_16x16x32_bf16(a, bq, acc, 0, 0, 0);
            }
            if ((lane & 15) == 0) {
              #pragma unroll
              for (int reg = 0; reg < 4; ++reg) {
                int tt = mt * 16 + (lane >> 4) * 4 + reg;
                esc[tt] = (tt < len) ? acc[reg] : -3.0e38f;
              }
            }
          }
        }
      }
      __syncthreads();   // B5: esc ready

      // phase 5: softmax m/denom (redundant per wave, butterfly), p -> psc
      float rinv;
      {
        float v0 = esc[lane], v1 = esc[lane + 64], v2 = esc[lane + 128], v3 = esc[lane + 192];
        float m = fmaxf(fmaxf(v0, v1), fmaxf(v2, v3));
        #pragma unroll
        for (int s = 32; s >= 1; s >>= 1) m = fmaxf(m, __shfl_xor(m, s));
        float p0 = __expf(v0 - m), p1 = __expf(v1 - m), p2 = __expf(v2 - m), p3 = __expf(v3 - m);
        float sv = p0 + p1 + p2 + p3;
        #pragma unroll
        for (int s = 32; s >= 1; s >>= 1) sv += __shfl_xor(sv, s);
        rinv = 1.f / sv;
        if (w < 4) psc[lane + (w << 6)] = (w == 0) ? p0 : (w == 1) ? p1 : (w == 2) ? p2 : p3;
      }
      __syncthreads();   // B6: psc ready

      // phase 6A: partial r — wave w owns t rows [w*32, w*32+32), thread owns 4 e cols
      {
        const int t0 = w * 32;
        const int tmax = (t0 + 32 < len) ? (t0 + 32) : len;
        float r0 = 0.f, r1 = 0.f, r2 = 0.f, r3 = 0.f;
        for (int tt = t0; tt < tmax; ++tt) {
          float p = psc[tt];
          ushort4v ev = *reinterpret_cast<const ushort4v*>(&emb[tt][lane * 4]);
          r0 += p * bf2f(ev[0]); r1 += p * bf2f(ev[1]);
          r2 += p * bf2f(ev[2]); r3 += p * bf2f(ev[3]);
        }
        f32x4 rv = {r0, r1, r2, r3};
        *reinterpret_cast<f32x4*>(&rpart[w][lane * 4]) = rv;
      }
      __syncthreads();   // B7: rpart ready

      // phase 6B: r[e] = (sum_slices) * rinv -> qs[256+e]; x prefetch (fallback)
      if (tid < H_) {
        float s = 0.f;
        #pragma unroll
        for (int sl = 0; sl < 8; ++sl) s += rpart[sl][tid];
        qs[H_ + tid] = f2bf(s * rinv);
        if (!USE_GX) qs[512 + tid] = f2bf(xnext);
      }
      // loop-top barrier (B1) fences qs writes
    }

    // zero padded outputs
    for (int tt = len + tid; tt < T_; tt += NT) out[(size_t)b * T_ + tt] = 0.f;
    __syncthreads();   // emb/qs/esc reuse fence before next molecule
  }
}

extern "C" void kernel_launch(void* const* d_in, const int* in_sizes, int n_in,
                              void* d_out, int out_size, void* d_ws, size_t ws_size,
                              hipStream_t stream) {
  const float* features = (const float*)d_in[0];
  const int*   lengths  = (const int*)d_in[1];
  const float* W_embed  = (const float*)d_in[2];
  const float* W_ih     = (const float*)d_in[3];
  const float* b_ih     = (const float*)d_in[4];
  const float* W_hh     = (const float*)d_in[5];
  const float* b_hh     = (const float*)d_in[6];
  const float* W_att    = (const float*)d_in[7];
  const float* W_final  = (const float*)d_in[8];
  const float* b_final  = (const float*)d_in[9];
  const float* q0       = (const float*)d_in[10];
  const float* c0       = (const float*)d_in[11];
  const float* r0       = (const float*)d_in[12];
  float* out = (float*)d_out;

  char* ws = (char*)d_ws;
  unsigned short* Bg    = (unsigned short*)(ws + 0);          // 1,572,864
  unsigned short* Bx    = (unsigned short*)(ws + 1572864);    //   524,288
  unsigned short* Ba    = (unsigned short*)(ws + 2097152);    //   131,072
  unsigned short* We    = (unsigned short*)(ws + 2228224);    //   131,072
  float*          bcomb = (float*)(ws + 2359296);             //     4,096
  int*            perm  = (int*)(ws + 2363392);               //     2,048
  unsigned short* gxw   = (unsigned short*)(ws + 2365440);    // 268,435,456
  const size_t need_gx = 2365440ull + 268435456ull;
  const int use_gx = (ws_size >= need_gx) ? 1 : 0;

  const int setup_elems = G4_ * K_ + G4_ * F_ + E_ * H_ + E_ * F_ + G4_;  // 1,180,672
  setup_pack<<<(setup_elems + 255) / 256, 256, 0, stream>>>(
      W_ih, W_hh, b_ih, b_hh, W_att, W_embed, Bg, Bx, Ba, We, bcomb);
  sort_kernel<<<1, B_, 0, stream>>>(lengths, perm);
  if (use_gx) {
    gx_kernel<<<B_, 256, 0, stream>>>(features, Bx, gxw);
    mol_kernel<1><<<NBLK, NT, 0, stream>>>(
        features, lengths, perm, Bg, Ba, We, bcomb,
        W_final, b_final, q0, c0, r0, gxw, out);
  } else {
    mol_kernel<0><<<NBLK, NT, 0, stream>>>(
        features, lengths, perm, Bg, Ba, We, bcomb,
        W_final, b_final, q0, c0, r0, gxw, out);
  }
}